// Round 2
// baseline (5911.193 us; speedup 1.0000x reference)
//
#include <hip/hip_runtime.h>
#include <math.h>

// Problem dims
#define kT 32
#define kB 128
#define kL 1024
#define kD 256

// ---------------- block reduction helpers (256 threads = 4 waves) -------------
__device__ __forceinline__ float blk_sum(float v, float* red, int tid){
  #pragma unroll
  for (int m = 32; m >= 1; m >>= 1) v += __shfl_xor(v, m, 64);
  __syncthreads();                 // protect red[] reuse from a previous call
  if ((tid & 63) == 0) red[tid >> 6] = v;
  __syncthreads();
  return red[0] + red[1] + red[2] + red[3];
}
__device__ __forceinline__ float blk_max(float v, float* red, int tid){
  #pragma unroll
  for (int m = 32; m >= 1; m >>= 1) v = fmaxf(v, __shfl_xor(v, m, 64));
  __syncthreads();
  if ((tid & 63) == 0) red[tid >> 6] = v;
  __syncthreads();
  return fmaxf(fmaxf(red[0], red[1]), fmaxf(red[2], red[3]));
}

// ---------------- init: copy states, mask dtype-sniff -> u8 -------------------
__global__ __launch_bounds__(256) void k_init(const float* hr0, const float* cr0,
        const float* hw0, const float* cw0, const unsigned char* maskraw,
        float* hr1, float* cr, float* hw1, float* cw, unsigned char* mbuf){
  int idx = blockIdx.x * 256 + threadIdx.x;
  if (idx < 131072){
    int which = idx >> 15, i = idx & 32767;
    if      (which == 0) hr1[i] = hr0[i];
    else if (which == 1) cr[i]  = cr0[i];
    else if (which == 2) hw1[i] = hw0[i];
    else                 cw[i]  = cw0[i];
  } else {
    int l = idx - 131072;   // 0..131071
    // Detect mask storage: int32 / u8(bool) / bf16 / fp32 from first 512 bytes.
    bool sawBig = false, sawOdd = false, saw3F1 = false;
    for (int i = 0; i < 512; i++){
      unsigned char c = maskraw[i];
      if (c > 1u) sawBig = true;
      if ((i & 3) != 0 && c != 0) sawOdd = true;
      if ((i & 3) == 1 && c == 0x3F) saw3F1 = true;
    }
    int mode = (!sawBig) ? (sawOdd ? 1 : 0) : (saw3F1 ? 2 : 3);
    unsigned char mv;
    if      (mode == 0) mv = (((const int*)maskraw)[l] != 0);
    else if (mode == 1) mv = (maskraw[l] != 0);
    else if (mode == 2) mv = ((maskraw[2*l] | maskraw[2*l+1]) != 0);
    else                mv = (((const unsigned int*)maskraw)[l] != 0);
    mbuf[l] = mv;
  }
}

// ---------------- read-LSTM step: gates = emb_t@Wih^T + hr@Whh^T, pointwise ---
// grid 64 = (4 b-tiles of 32) x (16 d-tiles of 16). thread: 1 d x 4 gates x 2 b.
__global__ __launch_bounds__(256) void k_A(const float* __restrict__ emb_t,
        const float* __restrict__ hr_old, float* __restrict__ hr_new,
        float* __restrict__ cr, const float* __restrict__ Wih,
        const float* __restrict__ Whh, const float* __restrict__ bih,
        const float* __restrict__ bhh){
  __shared__ float xs[256][34];
  int bb = blockIdx.x >> 4, db = blockIdx.x & 15;
  int b0 = bb * 32, d0 = db * 16, tid = threadIdx.x;
  int dd = tid & 15, bg = tid >> 4;
  int d = d0 + dd, r0 = bg * 2;
  float acc[4][2] = {{0,0},{0,0},{0,0},{0,0}};
  // pass 1: emb_t x Wih
  for (int i = tid; i < 32 * 256; i += 256){
    int k = i & 255, r = i >> 8;
    xs[k][r] = emb_t[(b0 + r) * 256 + k];
  }
  __syncthreads();
  for (int k0 = 0; k0 < 256; k0 += 4){
    float wf[4][4];
    #pragma unroll
    for (int g = 0; g < 4; g++){
      float4 w4 = *(const float4*)(Wih + (size_t)(g * 256 + d) * 256 + k0);
      wf[g][0] = w4.x; wf[g][1] = w4.y; wf[g][2] = w4.z; wf[g][3] = w4.w;
    }
    #pragma unroll
    for (int kk = 0; kk < 4; kk++){
      float2 x01 = *(const float2*)&xs[k0 + kk][r0];
      #pragma unroll
      for (int g = 0; g < 4; g++){
        acc[g][0] += wf[g][kk] * x01.x;
        acc[g][1] += wf[g][kk] * x01.y;
      }
    }
  }
  __syncthreads();
  // pass 2: hr_old x Whh
  for (int i = tid; i < 32 * 256; i += 256){
    int k = i & 255, r = i >> 8;
    xs[k][r] = hr_old[(b0 + r) * 256 + k];
  }
  __syncthreads();
  for (int k0 = 0; k0 < 256; k0 += 4){
    float wf[4][4];
    #pragma unroll
    for (int g = 0; g < 4; g++){
      float4 w4 = *(const float4*)(Whh + (size_t)(g * 256 + d) * 256 + k0);
      wf[g][0] = w4.x; wf[g][1] = w4.y; wf[g][2] = w4.z; wf[g][3] = w4.w;
    }
    #pragma unroll
    for (int kk = 0; kk < 4; kk++){
      float2 x01 = *(const float2*)&xs[k0 + kk][r0];
      #pragma unroll
      for (int g = 0; g < 4; g++){
        acc[g][0] += wf[g][kk] * x01.x;
        acc[g][1] += wf[g][kk] * x01.y;
      }
    }
  }
  #pragma unroll
  for (int rr = 0; rr < 2; rr++){
    int b = b0 + r0 + rr;
    float gi = acc[0][rr] + bih[      d] + bhh[      d];
    float gf = acc[1][rr] + bih[256 + d] + bhh[256 + d];
    float gg = acc[2][rr] + bih[512 + d] + bhh[512 + d];
    float go = acc[3][rr] + bih[768 + d] + bhh[768 + d];
    float i_ = 1.f / (1.f + expf(-gi));
    float f_ = 1.f / (1.f + expf(-gf));
    float g_ = tanhf(gg);
    float o_ = 1.f / (1.f + expf(-go));
    float c2 = f_ * cr[b * 256 + d] + i_ * g_;
    cr[b * 256 + d] = c2;
    hr_new[b * 256 + d] = o_ * tanhf(c2);
  }
}

// ---------------- attention (+fused comp softmax): one block per batch row ----
__global__ __launch_bounds__(256) void k_C(int t, const float* __restrict__ hr,
        const float* __restrict__ hw_prev, const float* __restrict__ M0,
        const unsigned char* __restrict__ mb, float* __restrict__ zp,
        const float* __restrict__ Wc, const float* __restrict__ bc,
        float* __restrict__ comp){
  __shared__ float hrs[256], hws[256], ms[256];
  __shared__ float sfull[1024];
  __shared__ float red[4];
  __shared__ float Mt[16][257];
  int b = blockIdx.x, tid = threadIdx.x;
  hrs[tid] = hr[b * 256 + tid];
  hws[tid] = hw_prev[b * 256 + tid];
  __syncthreads();

  if (t == 0){
    // flash-style single pass over M0[b] : z logits + online softmax + m accum
    float run_max = -INFINITY, S = 0.f, macc = 0.f;   // macc for d = tid
    for (int l0 = 0; l0 < 1024; l0 += 16){
      for (int i = tid; i < 1024; i += 256){
        int g = i >> 6, k4 = (i & 63) << 2;
        float4 v = *(const float4*)(M0 + ((size_t)b * 1024 + l0 + g) * 256 + k4);
        Mt[g][k4] = v.x; Mt[g][k4+1] = v.y; Mt[g][k4+2] = v.z; Mt[g][k4+3] = v.w;
      }
      __syncthreads();
      int g = tid >> 4, ii = tid & 15;
      float part = 0.f;
      #pragma unroll
      for (int q = 0; q < 16; q++) part += hrs[ii * 16 + q] * Mt[g][ii * 16 + q];
      #pragma unroll
      for (int m = 1; m < 16; m <<= 1) part += __shfl_xor(part, m, 64);
      if (ii == 0) sfull[l0 + g] = mb[b * 1024 + l0 + g] ? -INFINITY : part;
      __syncthreads();
      float tmax = -INFINITY;
      #pragma unroll
      for (int q = 0; q < 16; q++) tmax = fmaxf(tmax, sfull[l0 + q]);
      float nm = fmaxf(run_max, tmax);
      if (nm != -INFINITY){
        float scale = expf(run_max - nm);   // run_max=-inf -> 0
        float addS = 0.f, addM = 0.f;
        #pragma unroll
        for (int q = 0; q < 16; q++){
          float p = expf(sfull[l0 + q] - nm);
          addS += p;
          addM += p * Mt[q][tid];
        }
        S = S * scale + addS;
        macc = macc * scale + addM;
        run_max = nm;
      }
      __syncthreads();
    }
    ms[tid] = macc / S;
    for (int i = tid; i < 1024; i += 256)
      zp[b * 1024 + i] = expf(sfull[i] - run_max) / S;   // masked -> 0
  } else {
    // factored memory: M = (1-zp) + hw_prev (x) zp
    float S1 = blk_sum(hrs[tid], red, tid);
    float S2 = blk_sum(hrs[tid] * hws[tid], red, tid);
    float sv[4], zv[4], pv[4];
    float lmax = -INFINITY;
    #pragma unroll
    for (int q = 0; q < 4; q++){
      int l = tid + q * 256;
      float zpl = zp[b * 1024 + l];
      float s = mb[b * 1024 + l] ? -INFINITY : (1.f - zpl) * S1 + zpl * S2;
      sv[q] = s; zv[q] = zpl;
      lmax = fmaxf(lmax, s);
    }
    float gmax = blk_max(lmax, red, tid);
    float ls = 0.f;
    #pragma unroll
    for (int q = 0; q < 4; q++){ pv[q] = expf(sv[q] - gmax); ls += pv[q]; }
    float gs = blk_sum(ls, red, tid);
    float A = 0.f, C = 0.f;
    #pragma unroll
    for (int q = 0; q < 4; q++){
      float z = pv[q] / gs;
      zp[b * 1024 + tid + q * 256] = z;
      A += z * (1.f - zv[q]);
      C += z * zv[q];
    }
    A = blk_sum(A, red, tid);
    C = blk_sum(C, red, tid);
    ms[tid] = A + hws[tid] * C;
  }
  __syncthreads();

  // comp = softmax( Wc @ concat(hr, m) + bc ) : thread tid -> output j = tid
  float e = bc[tid];
  const float* wr = Wc + (size_t)tid * 512;
  for (int k0 = 0; k0 < 256; k0 += 4){
    float4 wa = *(const float4*)(wr + k0);
    float4 wb = *(const float4*)(wr + 256 + k0);
    e += wa.x * hrs[k0]     + wa.y * hrs[k0 + 1]
       + wa.z * hrs[k0 + 2] + wa.w * hrs[k0 + 3];
    e += wb.x * ms[k0]      + wb.y * ms[k0 + 1]
       + wb.z * ms[k0 + 2]  + wb.w * ms[k0 + 3];
  }
  float cm = blk_max(e, red, tid);
  float pe = expf(e - cm);
  float cs = blk_sum(pe, red, tid);
  comp[b * 256 + tid] = pe / cs;
}

// ---------------- write-LSTM step (K=512: comp then hw), pointwise + out ------
__global__ __launch_bounds__(256) void k_E(const float* __restrict__ comp,
        const float* __restrict__ hw_old, float* __restrict__ hw_new,
        float* __restrict__ cw, const float* __restrict__ Wih,
        const float* __restrict__ Whh, const float* __restrict__ bih,
        const float* __restrict__ bhh, float* __restrict__ outp){
  __shared__ float xs[256][34];
  int bb = blockIdx.x >> 4, db = blockIdx.x & 15;
  int b0 = bb * 32, d0 = db * 16, tid = threadIdx.x;
  int dd = tid & 15, bg = tid >> 4;
  int d = d0 + dd, r0 = bg * 2;
  float acc[4][2] = {{0,0},{0,0},{0,0},{0,0}};
  // pass 1: comp x Wih_w
  for (int i = tid; i < 32 * 256; i += 256){
    int k = i & 255, r = i >> 8;
    xs[k][r] = comp[(b0 + r) * 256 + k];
  }
  __syncthreads();
  for (int k0 = 0; k0 < 256; k0 += 4){
    float wf[4][4];
    #pragma unroll
    for (int g = 0; g < 4; g++){
      float4 w4 = *(const float4*)(Wih + (size_t)(g * 256 + d) * 256 + k0);
      wf[g][0] = w4.x; wf[g][1] = w4.y; wf[g][2] = w4.z; wf[g][3] = w4.w;
    }
    #pragma unroll
    for (int kk = 0; kk < 4; kk++){
      float2 x01 = *(const float2*)&xs[k0 + kk][r0];
      #pragma unroll
      for (int g = 0; g < 4; g++){
        acc[g][0] += wf[g][kk] * x01.x;
        acc[g][1] += wf[g][kk] * x01.y;
      }
    }
  }
  __syncthreads();
  // pass 2: hw_old x Whh_w
  for (int i = tid; i < 32 * 256; i += 256){
    int k = i & 255, r = i >> 8;
    xs[k][r] = hw_old[(b0 + r) * 256 + k];
  }
  __syncthreads();
  for (int k0 = 0; k0 < 256; k0 += 4){
    float wf[4][4];
    #pragma unroll
    for (int g = 0; g < 4; g++){
      float4 w4 = *(const float4*)(Whh + (size_t)(g * 256 + d) * 256 + k0);
      wf[g][0] = w4.x; wf[g][1] = w4.y; wf[g][2] = w4.z; wf[g][3] = w4.w;
    }
    #pragma unroll
    for (int kk = 0; kk < 4; kk++){
      float2 x01 = *(const float2*)&xs[k0 + kk][r0];
      #pragma unroll
      for (int g = 0; g < 4; g++){
        acc[g][0] += wf[g][kk] * x01.x;
        acc[g][1] += wf[g][kk] * x01.y;
      }
    }
  }
  #pragma unroll
  for (int rr = 0; rr < 2; rr++){
    int b = b0 + r0 + rr;
    float gi = acc[0][rr] + bih[      d] + bhh[      d];
    float gf = acc[1][rr] + bih[256 + d] + bhh[256 + d];
    float gg = acc[2][rr] + bih[512 + d] + bhh[512 + d];
    float go = acc[3][rr] + bih[768 + d] + bhh[768 + d];
    float i_ = 1.f / (1.f + expf(-gi));
    float f_ = 1.f / (1.f + expf(-gf));
    float g_ = tanhf(gg);
    float o_ = 1.f / (1.f + expf(-go));
    float c2 = f_ * cw[b * 256 + d] + i_ * g_;
    cw[b * 256 + d] = c2;
    float h2 = o_ * tanhf(c2);
    hw_new[b * 256 + d] = h2;
    outp[b * 256 + d] = h2;
  }
}

// ---------------- final: states + materialize M = (1-z) + hw (x) z ------------
__global__ __launch_bounds__(256) void k_final(const float* __restrict__ hr,
        const float* __restrict__ cr, const float* __restrict__ hw,
        const float* __restrict__ cw, const float* __restrict__ zp,
        float* __restrict__ out){
  int blk = blockIdx.x;
  if (blk < 2048){
    float* Mout = out + 1179648;       // after outputs + 4 states
    int base = blk * 256 + threadIdx.x;
    for (int g = base; g < 8388608; g += 524288){   // float4 groups
      int b = g >> 16;                 // 65536 groups per batch row
      int rem = g & 65535;
      int l = rem >> 6;                // 64 groups per memory slot
      int d0 = (rem & 63) << 2;
      float z = zp[b * 1024 + l];
      float omz = 1.f - z;
      float4 v;
      v.x = omz + hw[b * 256 + d0    ] * z;
      v.y = omz + hw[b * 256 + d0 + 1] * z;
      v.z = omz + hw[b * 256 + d0 + 2] * z;
      v.w = omz + hw[b * 256 + d0 + 3] * z;
      *(float4*)(Mout + (size_t)g * 4) = v;
    }
  } else {
    int i = (blk - 2048) * 256 + threadIdx.x;   // 0..131071
    int which = i >> 15, k = i & 32767;
    float v = (which == 0) ? hr[k] : (which == 1) ? cr[k]
            : (which == 2) ? hw[k] : cw[k];
    out[1048576 + which * 32768 + k] = v;
  }
}

extern "C" void kernel_launch(void* const* d_in, const int* in_sizes, int n_in,
                              void* d_out, int out_size, void* d_ws, size_t ws_size,
                              hipStream_t stream){
  const float* emb   = (const float*)d_in[0];
  const float* hr0   = (const float*)d_in[1];
  const float* cr0   = (const float*)d_in[2];
  const float* hw0   = (const float*)d_in[3];
  const float* cw0   = (const float*)d_in[4];
  const float* M0    = (const float*)d_in[5];
  const unsigned char* maskraw = (const unsigned char*)d_in[6];
  const float* Wih_r = (const float*)d_in[7];
  const float* Whh_r = (const float*)d_in[8];
  const float* bih_r = (const float*)d_in[9];
  const float* bhh_r = (const float*)d_in[10];
  const float* Wc    = (const float*)d_in[11];
  const float* bc    = (const float*)d_in[12];
  const float* Wih_w = (const float*)d_in[13];
  const float* Whh_w = (const float*)d_in[14];
  const float* bih_w = (const float*)d_in[15];
  const float* bhh_w = (const float*)d_in[16];
  float* out = (float*)d_out;

  float* ws   = (float*)d_ws;
  float* hrb  = ws;                 // double buffer = 2*32768 f
  float* crs  = hrb + 65536;        // 32768 f
  float* hwb  = crs + 32768;        // 2*32768 f
  float* cws  = hwb + 65536;        // 32768 f
  float* zp   = cws + 32768;        // B*L = 131072 f
  float* comp = zp + 131072;        // 32768 f
  unsigned char* mbuf = (unsigned char*)(comp + 32768);  // B*L bytes

  k_init<<<dim3(1024), dim3(256), 0, stream>>>(hr0, cr0, hw0, cw0, maskraw,
        hrb + 32768, crs, hwb + 32768, cws, mbuf);

  for (int t = 0; t < kT; t++){
    const float* hr_old = hrb + ((t + 1) & 1) * 32768;
    float* hr_new       = hrb + (t & 1) * 32768;
    const float* hw_old = hwb + ((t + 1) & 1) * 32768;
    float* hw_new       = hwb + (t & 1) * 32768;
    k_A<<<dim3(64), dim3(256), 0, stream>>>(emb + (size_t)t * 32768, hr_old,
          hr_new, crs, Wih_r, Whh_r, bih_r, bhh_r);
    k_C<<<dim3(128), dim3(256), 0, stream>>>(t, hr_new, hw_old, M0, mbuf, zp,
          Wc, bc, comp);
    k_E<<<dim3(64), dim3(256), 0, stream>>>(comp, hw_old, hw_new, cws,
          Wih_w, Whh_w, bih_w, bhh_w, out + (size_t)t * 32768);
  }
  k_final<<<dim3(2560), dim3(256), 0, stream>>>(hrb + 32768, crs, hwb + 32768,
        cws, zp, out);
}

// Round 3
// 2699.232 us; speedup vs baseline: 2.1900x; 2.1900x over previous
//
#include <hip/hip_runtime.h>
#include <math.h>

typedef unsigned short u16;

// Problem dims
#define kT 32
#define kB 128
#define kL 1024
#define kD 256

#define OUT_STATES 1048576   // T*B*D
#define OUT_M      1179648   // + 4*B*D

__device__ __forceinline__ u16 f2b(float f){
  union { float fv; unsigned int u; } v; v.fv = f;
  unsigned int u = v.u;
  return (u16)((u + 0x7FFFu + ((u >> 16) & 1u)) >> 16);  // RNE
}
__device__ __forceinline__ float bflo(unsigned u){
  union { unsigned x; float f; } v; v.x = u << 16; return v.f;
}
__device__ __forceinline__ float bfhi(unsigned u){
  union { unsigned x; float f; } v; v.x = u & 0xFFFF0000u; return v.f;
}

// dot of 8 bf16 weights (one uint4) with 8 fp32 x values; dual accumulators
__device__ __forceinline__ void dot8(float& a0, float& a1, uint4 w, const float* x){
  float4 x0 = *(const float4*)(x);
  float4 x1 = *(const float4*)(x + 4);
  a0 += bflo(w.x) * x0.x;  a1 += bfhi(w.x) * x0.y;
  a0 += bflo(w.y) * x0.z;  a1 += bfhi(w.y) * x0.w;
  a0 += bflo(w.z) * x1.x;  a1 += bfhi(w.z) * x1.y;
  a0 += bflo(w.w) * x1.z;  a1 += bfhi(w.w) * x1.w;
}
// K multiple of 32; wrow 16B-aligned; x in LDS (broadcast reads)
__device__ __forceinline__ float dotK(const u16* __restrict__ wrow,
                                      const float* x, int K){
  float a0 = 0.f, a1 = 0.f;
  for (int k0 = 0; k0 < K; k0 += 32){
    uint4 wa = *(const uint4*)(wrow + k0);
    uint4 wb = *(const uint4*)(wrow + k0 + 8);
    uint4 wc = *(const uint4*)(wrow + k0 + 16);
    uint4 wd = *(const uint4*)(wrow + k0 + 24);
    dot8(a0, a1, wa, x + k0);
    dot8(a0, a1, wb, x + k0 + 8);
    dot8(a0, a1, wc, x + k0 + 16);
    dot8(a0, a1, wd, x + k0 + 24);
  }
  return a0 + a1;
}

// ---- block reductions over 1024 threads (16 waves) ---------------------------
__device__ __forceinline__ float bsum(float v, volatile float* red, int tid){
  #pragma unroll
  for (int m = 32; m >= 1; m >>= 1) v += __shfl_xor(v, m, 64);
  __syncthreads();
  if ((tid & 63) == 0) red[tid >> 6] = v;
  __syncthreads();
  float r = 0.f;
  #pragma unroll
  for (int i = 0; i < 16; i++) r += red[i];
  return r;
}
__device__ __forceinline__ float bmax(float v, volatile float* red, int tid){
  #pragma unroll
  for (int m = 32; m >= 1; m >>= 1) v = fmaxf(v, __shfl_xor(v, m, 64));
  __syncthreads();
  if ((tid & 63) == 0) red[tid >> 6] = v;
  __syncthreads();
  float r = -INFINITY;
  #pragma unroll
  for (int i = 0; i < 16; i++) r = fmaxf(r, red[i]);
  return r;
}

// ---- prep: weights -> bf16 (concat K layout), biases summed, mask -> u8 ------
// item map: [0,524288) WA | [524288,1048576) WE | then Wc 131072 | bA 1024 |
//           bE 1024 | bc 256 | mask 131072
__global__ __launch_bounds__(1024) void k_prep(
        const float* __restrict__ Wih_r, const float* __restrict__ Whh_r,
        const float* __restrict__ bih_r, const float* __restrict__ bhh_r,
        const float* __restrict__ Wc,    const float* __restrict__ bc,
        const float* __restrict__ Wih_w, const float* __restrict__ Whh_w,
        const float* __restrict__ bih_w, const float* __restrict__ bhh_w,
        const unsigned char* __restrict__ maskraw,
        u16* WA, u16* WE, u16* Wcb, float* bA, float* bE, float* bcf,
        unsigned char* mbuf){
  int idx = blockIdx.x * 1024 + threadIdx.x;
  if (idx < 524288){
    int col = idx >> 9, k = idx & 511;
    float v = (k < 256) ? Wih_r[col * 256 + k] : Whh_r[col * 256 + k - 256];
    WA[idx] = f2b(v);
  } else if (idx < 1048576){
    int i = idx - 524288;
    int col = i >> 9, k = i & 511;
    float v = (k < 256) ? Wih_w[col * 256 + k] : Whh_w[col * 256 + k - 256];
    WE[i] = f2b(v);
  } else if (idx < 1179648){
    int i = idx - 1048576;
    Wcb[i] = f2b(Wc[i]);
  } else if (idx < 1180672){
    int i = idx - 1179648;
    bA[i] = bih_r[i] + bhh_r[i];
  } else if (idx < 1181696){
    int i = idx - 1180672;
    bE[i] = bih_w[i] + bhh_w[i];
  } else if (idx < 1181952){
    int i = idx - 1181696;
    bcf[i] = bc[i];
  } else if (idx < 1313024){
    int l = idx - 1181952;
    // Detect mask storage: int32 / u8(bool) / bf16 / fp32 from first 512 bytes.
    bool sawBig = false, sawOdd = false, saw3F1 = false;
    for (int i = 0; i < 512; i++){
      unsigned char c = maskraw[i];
      if (c > 1u) sawBig = true;
      if ((i & 3) != 0 && c != 0) sawOdd = true;
      if ((i & 3) == 1 && c == 0x3F) saw3F1 = true;
    }
    int mode = (!sawBig) ? (sawOdd ? 1 : 0) : (saw3F1 ? 2 : 3);
    unsigned char mv;
    if      (mode == 0) mv = (((const int*)maskraw)[l] != 0);
    else if (mode == 1) mv = (maskraw[l] != 0);
    else if (mode == 2) mv = ((maskraw[2*l] | maskraw[2*l+1]) != 0);
    else                mv = (((const unsigned int*)maskraw)[l] != 0);
    mbuf[l] = mv;
  }
}

// ---- main: one block per batch row runs the entire 32-step recurrence --------
__global__ __launch_bounds__(1024, 4) void k_main(
        const float* __restrict__ emb, const float* __restrict__ hr0,
        const float* __restrict__ cr0, const float* __restrict__ hw0,
        const float* __restrict__ cw0, const float* __restrict__ M0,
        const u16* __restrict__ WA, const u16* __restrict__ WE,
        const u16* __restrict__ Wcb, const float* __restrict__ bA,
        const float* __restrict__ bE, const float* __restrict__ bcf,
        const unsigned char* __restrict__ mbuf, float* __restrict__ out){
  __shared__ float ls_x[512];           // [emb_t | hr]
  __shared__ float ls_y[512];           // [comp | hw]
  __shared__ float cr_l[256], cw_l[256];
  __shared__ float gbuf[1024];
  __shared__ float cbuf[512];           // [hr | m] for comp GEMM
  __shared__ float z_lds[1024];         // t=0 logits; final z
  __shared__ float red16[16], wred[16], sred[16];
  __shared__ float mlds[16 * 260];      // t=0 per-wave macc partials
  __shared__ float psum[4 * 260];       // comp K-split partials
  __shared__ unsigned char mk[1024];

  int b = blockIdx.x, tid = threadIdx.x;
  if (tid < 256){
    ls_x[256 + tid] = hr0[b * 256 + tid];
    cr_l[tid]       = cr0[b * 256 + tid];
    ls_y[256 + tid] = hw0[b * 256 + tid];
    cw_l[tid]       = cw0[b * 256 + tid];
  }
  unsigned char mreg = mbuf[b * 1024 + tid];
  mk[tid] = mreg;
  float zreg = 0.f;
  __syncthreads();

  for (int t = 0; t < kT; t++){
    // ---------- Phase A: read-LSTM ----------
    if (tid < 256) ls_x[tid] = emb[(size_t)t * 32768 + b * 256 + tid];
    __syncthreads();
    gbuf[tid] = dotK(WA + (size_t)tid * 512, ls_x, 512) + bA[tid];
    __syncthreads();
    if (tid < 256){
      float i_ = 1.f / (1.f + expf(-gbuf[tid]));
      float f_ = 1.f / (1.f + expf(-gbuf[256 + tid]));
      float g_ = tanhf(gbuf[512 + tid]);
      float o_ = 1.f / (1.f + expf(-gbuf[768 + tid]));
      float c2 = f_ * cr_l[tid] + i_ * g_;
      cr_l[tid] = c2;
      ls_x[256 + tid] = o_ * tanhf(c2);   // hr_new
    }
    __syncthreads();

    // ---------- Phase C: attention ----------
    if (t == 0){
      // per-wave flash scan over 64 rows of M0[b]
      int w = tid >> 6, lane = tid & 63;
      float4 hrv = *(const float4*)&ls_x[256 + lane * 4];
      float run_max = -INFINITY, S = 0.f;
      float m0 = 0.f, m1 = 0.f, m2 = 0.f, m3 = 0.f;
      for (int l = w * 64; l < w * 64 + 64; ++l){
        float4 Mv = *(const float4*)(M0 + ((size_t)b * 1024 + l) * 256 + lane * 4);
        float part = Mv.x * hrv.x + Mv.y * hrv.y + Mv.z * hrv.z + Mv.w * hrv.w;
        #pragma unroll
        for (int mm = 32; mm >= 1; mm >>= 1) part += __shfl_xor(part, mm, 64);
        float s = mk[l] ? -INFINITY : part;
        if (lane == 0) z_lds[l] = s;
        float nm = fmaxf(run_max, s);
        if (nm > -INFINITY){
          float sc = expf(run_max - nm);
          float p  = expf(s - nm);
          S = S * sc + p;
          m0 = m0 * sc + p * Mv.x;  m1 = m1 * sc + p * Mv.y;
          m2 = m2 * sc + p * Mv.z;  m3 = m3 * sc + p * Mv.w;
          run_max = nm;
        }
      }
      if (lane == 0){ wred[w] = run_max; sred[w] = S; }
      mlds[w * 260 + lane * 4 + 0] = m0;
      mlds[w * 260 + lane * 4 + 1] = m1;
      mlds[w * 260 + lane * 4 + 2] = m2;
      mlds[w * 260 + lane * 4 + 3] = m3;
      __syncthreads();
      float gmax = -INFINITY;
      #pragma unroll
      for (int w2 = 0; w2 < 16; w2++) gmax = fmaxf(gmax, wred[w2]);
      float Sg = 0.f;
      #pragma unroll
      for (int w2 = 0; w2 < 16; w2++) Sg += sred[w2] * expf(wred[w2] - gmax);
      zreg = expf(z_lds[tid] - gmax) / Sg;
      if (tid < 256){
        float mv = 0.f;
        #pragma unroll
        for (int w2 = 0; w2 < 16; w2++)
          mv += mlds[w2 * 260 + tid] * expf(wred[w2] - gmax);
        cbuf[256 + tid] = mv / Sg;
      }
    } else {
      // factored memory: M = (1-zp) + hw_prev (x) zp
      float hrv = (tid < 256) ? ls_x[256 + tid] : 0.f;
      float hwv = (tid < 256) ? ls_y[256 + tid] : 0.f;
      float S1 = bsum(hrv, red16, tid);
      float S2 = bsum(hrv * hwv, red16, tid);
      float zold = zreg;
      float s = mreg ? -INFINITY : (1.f - zold) * S1 + zold * S2;
      float gmax = bmax(s, red16, tid);
      float p = expf(s - gmax);            // -inf -> 0
      float Ssum = bsum(p, red16, tid);
      float znew = p / Ssum;
      float Ab = bsum(znew * (1.f - zold), red16, tid);
      float Cb = bsum(znew * zold, red16, tid);
      zreg = znew;
      if (tid < 256) cbuf[256 + tid] = Ab + ls_y[256 + tid] * Cb;
    }
    if (tid < 256) cbuf[tid] = ls_x[256 + tid];   // hr
    __syncthreads();

    // ---------- comp = softmax(Wc @ [hr;m] + bc) ----------
    {
      int col = tid & 255, sl = tid >> 8;
      psum[sl * 260 + col] =
          dotK(Wcb + (size_t)col * 512 + sl * 128, cbuf + sl * 128, 128);
    }
    __syncthreads();
    {
      float e = (tid < 256)
          ? (psum[tid] + psum[260 + tid] + psum[520 + tid] + psum[780 + tid]
             + bcf[tid])
          : -INFINITY;
      float emax = bmax(e, red16, tid);
      float pe = (tid < 256) ? expf(e - emax) : 0.f;
      float esum = bsum(pe, red16, tid);
      if (tid < 256) ls_y[tid] = pe / esum;
    }
    __syncthreads();

    // ---------- Phase E: write-LSTM ----------
    gbuf[tid] = dotK(WE + (size_t)tid * 512, ls_y, 512) + bE[tid];
    __syncthreads();
    if (tid < 256){
      float i_ = 1.f / (1.f + expf(-gbuf[tid]));
      float f_ = 1.f / (1.f + expf(-gbuf[256 + tid]));
      float g_ = tanhf(gbuf[512 + tid]);
      float o_ = 1.f / (1.f + expf(-gbuf[768 + tid]));
      float c2 = f_ * cw_l[tid] + i_ * g_;
      cw_l[tid] = c2;
      float h2 = o_ * tanhf(c2);
      ls_y[256 + tid] = h2;
      out[(size_t)t * 32768 + b * 256 + tid] = h2;
    }
    __syncthreads();
  }

  // ---------- epilogue: states + M = (1-z) + hw (x) z ----------
  if (tid < 256){
    out[OUT_STATES          + b * 256 + tid] = ls_x[256 + tid];  // hr
    out[OUT_STATES +  32768 + b * 256 + tid] = cr_l[tid];        // cr
    out[OUT_STATES +  65536 + b * 256 + tid] = ls_y[256 + tid];  // hw
    out[OUT_STATES +  98304 + b * 256 + tid] = cw_l[tid];        // cw
  }
  z_lds[tid] = zreg;
  __syncthreads();
  float* Mout = out + OUT_M + (size_t)b * 262144;
  for (int g = tid; g < 65536; g += 1024){
    int l = g >> 6, d0 = (g & 63) << 2;
    float z = z_lds[l], omz = 1.f - z;
    float4 h4 = *(const float4*)&ls_y[256 + d0];
    float4 v;
    v.x = omz + h4.x * z;  v.y = omz + h4.y * z;
    v.z = omz + h4.z * z;  v.w = omz + h4.w * z;
    *(float4*)(Mout + (size_t)l * 256 + d0) = v;
  }
}

extern "C" void kernel_launch(void* const* d_in, const int* in_sizes, int n_in,
                              void* d_out, int out_size, void* d_ws, size_t ws_size,
                              hipStream_t stream){
  const float* emb   = (const float*)d_in[0];
  const float* hr0   = (const float*)d_in[1];
  const float* cr0   = (const float*)d_in[2];
  const float* hw0   = (const float*)d_in[3];
  const float* cw0   = (const float*)d_in[4];
  const float* M0    = (const float*)d_in[5];
  const unsigned char* maskraw = (const unsigned char*)d_in[6];
  const float* Wih_r = (const float*)d_in[7];
  const float* Whh_r = (const float*)d_in[8];
  const float* bih_r = (const float*)d_in[9];
  const float* bhh_r = (const float*)d_in[10];
  const float* Wc    = (const float*)d_in[11];
  const float* bc    = (const float*)d_in[12];
  const float* Wih_w = (const float*)d_in[13];
  const float* Whh_w = (const float*)d_in[14];
  const float* bih_w = (const float*)d_in[15];
  const float* bhh_w = (const float*)d_in[16];
  float* out = (float*)d_out;

  char* ws = (char*)d_ws;
  u16* WA   = (u16*)(ws);                       // 524288 u16 = 1 MB
  u16* WE   = (u16*)(ws + 1048576);             // 1 MB
  u16* Wcb  = (u16*)(ws + 2097152);             // 256 KB
  float* bA = (float*)(ws + 2359296);           // 4 KB
  float* bE = (float*)(ws + 2363392);           // 4 KB
  float* bcf= (float*)(ws + 2367488);           // 1 KB
  unsigned char* mbuf = (unsigned char*)(ws + 2368512);  // 128 KB

  k_prep<<<dim3(1283), dim3(1024), 0, stream>>>(
      Wih_r, Whh_r, bih_r, bhh_r, Wc, bc, Wih_w, Whh_w, bih_w, bhh_w,
      maskraw, WA, WE, Wcb, bA, bE, bcf, mbuf);
  k_main<<<dim3(128), dim3(1024), 0, stream>>>(
      emb, hr0, cr0, hw0, cw0, M0, WA, WE, Wcb, bA, bE, bcf, mbuf, out);
}

// Round 4
// 1098.502 us; speedup vs baseline: 5.3811x; 2.4572x over previous
//
#include <hip/hip_runtime.h>
#include <math.h>

typedef unsigned short u16;
typedef unsigned int u32;
typedef __attribute__((ext_vector_type(2))) _Float16 h2;

#define kT 32
#define OUT_STATES 1048576   // T*B*D
#define OUT_M      1179648   // + 4*B*D

union H2U { u32 u; h2 h; };

__device__ __forceinline__ float dot2u(u32 w, u32 x, float acc){
  H2U a; a.u = w; H2U b; b.u = x;
#if __has_builtin(__builtin_amdgcn_fdot2)
  return __builtin_amdgcn_fdot2(a.h, b.h, acc, false);
#else
  acc += (float)a.h.x * (float)b.h.x;
  acc += (float)a.h.y * (float)b.h.y;
  return acc;
#endif
}

__device__ __forceinline__ u32 packf16(float x, float y){
  H2U v; v.h.x = (_Float16)x; v.h.y = (_Float16)y; return v.u;
}

// ---- prep: weights -> packed f16 [k/2][col] layout, biases summed, mask ------
// idx map: WAp [0,262144) | WEp [262144,524288) | Wcp [524288,589824) |
//          bA [589824,590848) | bE [590848,591872) | bc [591872,592128) |
//          mask [592128,723200)
__global__ __launch_bounds__(1024) void k_prep(
        const float* __restrict__ Wih_r, const float* __restrict__ Whh_r,
        const float* __restrict__ bih_r, const float* __restrict__ bhh_r,
        const float* __restrict__ Wc,    const float* __restrict__ bc,
        const float* __restrict__ Wih_w, const float* __restrict__ Whh_w,
        const float* __restrict__ bih_w, const float* __restrict__ bhh_w,
        const unsigned char* __restrict__ maskraw,
        u32* WAp, u32* WEp, u32* Wcp, float* bA, float* bE, float* bcf,
        unsigned char* mbuf){
  int idx = blockIdx.x * 1024 + threadIdx.x;
  if (idx < 262144){
    int kp = idx >> 10, col = idx & 1023;
    int k0 = 2 * kp;
    float v0 = (k0 < 256) ? Wih_r[col * 256 + k0] : Whh_r[col * 256 + k0 - 256];
    float v1 = (k0 + 1 < 256) ? Wih_r[col * 256 + k0 + 1]
                              : Whh_r[col * 256 + k0 + 1 - 256];
    WAp[idx] = packf16(v0, v1);
  } else if (idx < 524288){
    int i = idx - 262144;
    int kp = i >> 10, col = i & 1023;
    int k0 = 2 * kp;
    float v0 = (k0 < 256) ? Wih_w[col * 256 + k0] : Whh_w[col * 256 + k0 - 256];
    float v1 = (k0 + 1 < 256) ? Wih_w[col * 256 + k0 + 1]
                              : Whh_w[col * 256 + k0 + 1 - 256];
    WEp[i] = packf16(v0, v1);
  } else if (idx < 589824){
    int i = idx - 524288;
    int kp = i >> 8, col = i & 255;
    int k0 = 2 * kp;
    Wcp[i] = packf16(Wc[col * 512 + k0], Wc[col * 512 + k0 + 1]);
  } else if (idx < 590848){
    int i = idx - 589824;
    bA[i] = bih_r[i] + bhh_r[i];
  } else if (idx < 591872){
    int i = idx - 590848;
    bE[i] = bih_w[i] + bhh_w[i];
  } else if (idx < 592128){
    int i = idx - 591872;
    bcf[i] = bc[i];
  } else if (idx < 723200){
    int l = idx - 592128;
    // Detect mask storage: int32 / u8(bool) / bf16 / fp32 from first 512 bytes.
    bool sawBig = false, sawOdd = false, saw3F1 = false;
    for (int i = 0; i < 512; i++){
      unsigned char c = maskraw[i];
      if (c > 1u) sawBig = true;
      if ((i & 3) != 0 && c != 0) sawOdd = true;
      if ((i & 3) == 1 && c == 0x3F) saw3F1 = true;
    }
    int mode = (!sawBig) ? (sawOdd ? 1 : 0) : (saw3F1 ? 2 : 3);
    unsigned char mv;
    if      (mode == 0) mv = (((const int*)maskraw)[l] != 0);
    else if (mode == 1) mv = (maskraw[l] != 0);
    else if (mode == 2) mv = ((maskraw[2*l] | maskraw[2*l+1]) != 0);
    else                mv = (((const unsigned int*)maskraw)[l] != 0);
    mbuf[l] = mv;
  }
}

// gemv: 1024 cols, K=512 (256 half2 rows). thread = (cg 4 cols, ks of 4 slices)
// Coalesced: lanes -> consecutive cg -> consecutive 16B. x broadcast from LDS.
__device__ __forceinline__ void gemv1024(const u32* __restrict__ W,
        const u32* xh, float* psum, int tid){
  int cg = tid & 255, ks = tid >> 8;
  const uint4* wp = (const uint4*)W + (size_t)ks * 64 * 256 + cg;
  const u32* xk = xh + ks * 64;
  float a0 = 0.f, a1 = 0.f, a2 = 0.f, a3 = 0.f;
  #pragma unroll 8
  for (int i = 0; i < 64; i++){
    uint4 wv = wp[(size_t)i * 256];
    u32 xp = xk[i];
    a0 = dot2u(wv.x, xp, a0);  a1 = dot2u(wv.y, xp, a1);
    a2 = dot2u(wv.z, xp, a2);  a3 = dot2u(wv.w, xp, a3);
  }
  float4 r; r.x = a0; r.y = a1; r.z = a2; r.w = a3;
  *(float4*)&psum[ks * 1024 + cg * 4] = r;
}

// ---- main: one block per batch row runs the entire 32-step recurrence --------
__global__ __launch_bounds__(1024, 4) void k_main(
        const float* __restrict__ emb, const float* __restrict__ hr0,
        const float* __restrict__ cr0, const float* __restrict__ hw0,
        const float* __restrict__ cw0, const float* __restrict__ M0,
        const u32* __restrict__ WAp, const u32* __restrict__ WEp,
        const u32* __restrict__ Wcp, const float* __restrict__ bA,
        const float* __restrict__ bE, const float* __restrict__ bcf,
        const unsigned char* __restrict__ mbuf, float* __restrict__ out){
  __shared__ u32 xh[256];                                   // packed f16 x
  __shared__ __attribute__((aligned(16))) float hr_f[256];
  __shared__ __attribute__((aligned(16))) float hw_f[256];
  __shared__ float m_f[256], comp_f[256], cr_l[256], cw_l[256];
  __shared__ float gbuf[1024];
  __shared__ __attribute__((aligned(16))) float psum[4160]; // gemv partials / t0 mlds
  __shared__ float z_lds[1024];
  __shared__ float redA[16], redB[16], redC[16], redD[16], wred[16], sred[16];
  __shared__ unsigned char mk[1024];

  int b = blockIdx.x, tid = threadIdx.x;
  int w = tid >> 6, lane = tid & 63;
  if (tid < 256){
    hr_f[tid] = hr0[b * 256 + tid];
    cr_l[tid] = cr0[b * 256 + tid];
    hw_f[tid] = hw0[b * 256 + tid];
    cw_l[tid] = cw0[b * 256 + tid];
  }
  unsigned char mreg = mbuf[b * 1024 + tid];
  mk[tid] = mreg;
  float zreg = 0.f;
  __syncthreads();

  for (int t = 0; t < kT; t++){
    // ---------- Phase A: read-LSTM ----------
    if (tid < 128){
      float2 e2 = *(const float2*)(emb + (size_t)t * 32768 + b * 256 + 2 * tid);
      xh[tid] = packf16(e2.x, e2.y);
    } else if (tid < 256){
      int j = tid - 128;
      xh[tid] = packf16(hr_f[2 * j], hr_f[2 * j + 1]);
    }
    __syncthreads();
    gemv1024(WAp, xh, psum, tid);
    __syncthreads();
    gbuf[tid] = psum[tid] + psum[1024 + tid] + psum[2048 + tid]
              + psum[3072 + tid] + bA[tid];
    __syncthreads();
    if (tid < 256){
      float i_ = 1.f / (1.f + expf(-gbuf[tid]));
      float f_ = 1.f / (1.f + expf(-gbuf[256 + tid]));
      float g_ = tanhf(gbuf[512 + tid]);
      float o_ = 1.f / (1.f + expf(-gbuf[768 + tid]));
      float c2 = f_ * cr_l[tid] + i_ * g_;
      cr_l[tid] = c2;
      hr_f[tid] = o_ * tanhf(c2);
    }
    __syncthreads();

    // ---------- Phase C: attention ----------
    if (t == 0){
      // per-wave flash scan over 64 rows of M0[b]
      float4 hrv = *(const float4*)&hr_f[lane * 4];
      float run_max = -INFINITY, S = 0.f;
      float m0 = 0.f, m1 = 0.f, m2 = 0.f, m3 = 0.f;
      for (int l = w * 64; l < w * 64 + 64; ++l){
        float4 Mv = *(const float4*)(M0 + ((size_t)b * 1024 + l) * 256 + lane * 4);
        float part = Mv.x * hrv.x + Mv.y * hrv.y + Mv.z * hrv.z + Mv.w * hrv.w;
        #pragma unroll
        for (int mm = 32; mm >= 1; mm >>= 1) part += __shfl_xor(part, mm, 64);
        float s = mk[l] ? -INFINITY : part;
        if (lane == 0) z_lds[l] = s;
        float nm = fmaxf(run_max, s);
        if (nm > -INFINITY){
          float sc = expf(run_max - nm);
          float p  = expf(s - nm);
          S = S * sc + p;
          m0 = m0 * sc + p * Mv.x;  m1 = m1 * sc + p * Mv.y;
          m2 = m2 * sc + p * Mv.z;  m3 = m3 * sc + p * Mv.w;
          run_max = nm;
        }
      }
      if (lane == 0){ wred[w] = run_max; sred[w] = S; }
      psum[w * 260 + lane * 4 + 0] = m0;
      psum[w * 260 + lane * 4 + 1] = m1;
      psum[w * 260 + lane * 4 + 2] = m2;
      psum[w * 260 + lane * 4 + 3] = m3;
      __syncthreads();
      float gmax = -INFINITY;
      #pragma unroll
      for (int w2 = 0; w2 < 16; w2++) gmax = fmaxf(gmax, wred[w2]);
      float Sg = 0.f;
      #pragma unroll
      for (int w2 = 0; w2 < 16; w2++) Sg += sred[w2] * expf(wred[w2] - gmax);
      zreg = expf(z_lds[tid] - gmax) / Sg;
      if (tid < 256){
        float mv = 0.f;
        #pragma unroll
        for (int w2 = 0; w2 < 16; w2++)
          mv += psum[w2 * 260 + tid] * expf(wred[w2] - gmax);
        m_f[tid] = mv / Sg;
      }
    } else {
      // factored memory: M = (1-zp) + hw_prev (x) zp
      float hrv = (tid < 256) ? hr_f[tid] : 0.f;
      float hwv = (tid < 256) ? hw_f[tid] : 0.f;
      float v1 = hrv, v2 = hrv * hwv;
      #pragma unroll
      for (int mm = 32; mm >= 1; mm >>= 1){
        v1 += __shfl_xor(v1, mm, 64);  v2 += __shfl_xor(v2, mm, 64);
      }
      if (lane == 0){ redA[w] = v1; redB[w] = v2; }
      __syncthreads();
      float S1 = 0.f, S2 = 0.f;
      #pragma unroll
      for (int i = 0; i < 16; i++){ S1 += redA[i]; S2 += redB[i]; }
      float zold = zreg;
      float s = mreg ? -INFINITY : (1.f - zold) * S1 + zold * S2;
      float mx = s;
      #pragma unroll
      for (int mm = 32; mm >= 1; mm >>= 1) mx = fmaxf(mx, __shfl_xor(mx, mm, 64));
      if (lane == 0) redC[w] = mx;
      __syncthreads();
      float gmax = -INFINITY;
      #pragma unroll
      for (int i = 0; i < 16; i++) gmax = fmaxf(gmax, redC[i]);
      float p = expf(s - gmax);            // -inf -> 0
      float ps = p;
      #pragma unroll
      for (int mm = 32; mm >= 1; mm >>= 1) ps += __shfl_xor(ps, mm, 64);
      if (lane == 0) redD[w] = ps;
      __syncthreads();
      float Ssum = 0.f;
      #pragma unroll
      for (int i = 0; i < 16; i++) Ssum += redD[i];
      float znew = p / Ssum;
      float a1 = znew * (1.f - zold), a2 = znew * zold;
      #pragma unroll
      for (int mm = 32; mm >= 1; mm >>= 1){
        a1 += __shfl_xor(a1, mm, 64);  a2 += __shfl_xor(a2, mm, 64);
      }
      if (lane == 0){ redA[w] = a1; redB[w] = a2; }
      __syncthreads();
      float Ab = 0.f, Cb = 0.f;
      #pragma unroll
      for (int i = 0; i < 16; i++){ Ab += redA[i]; Cb += redB[i]; }
      zreg = znew;
      if (tid < 256) m_f[tid] = Ab + hw_f[tid] * Cb;
    }
    __syncthreads();

    // ---------- comp = softmax(Wc @ [hr;m] + bc) ----------
    if (tid < 128) xh[tid] = packf16(hr_f[2 * tid], hr_f[2 * tid + 1]);
    else if (tid < 256){
      int j = tid - 128;
      xh[tid] = packf16(m_f[2 * j], m_f[2 * j + 1]);
    }
    __syncthreads();
    {
      int cg = tid & 63, ks = tid >> 6;
      const uint4* wp = (const uint4*)Wcp + ks * 16 * 64 + cg;
      const u32* xk = xh + ks * 16;
      float a0 = 0.f, a1 = 0.f, a2 = 0.f, a3 = 0.f;
      #pragma unroll
      for (int i = 0; i < 16; i++){
        uint4 wv = wp[i * 64];
        u32 xp = xk[i];
        a0 = dot2u(wv.x, xp, a0);  a1 = dot2u(wv.y, xp, a1);
        a2 = dot2u(wv.z, xp, a2);  a3 = dot2u(wv.w, xp, a3);
      }
      float4 r; r.x = a0; r.y = a1; r.z = a2; r.w = a3;
      *(float4*)&psum[ks * 256 + cg * 4] = r;
    }
    __syncthreads();
    {
      float e = -INFINITY;
      if (tid < 256){
        e = bcf[tid];
        #pragma unroll
        for (int s2 = 0; s2 < 16; s2++) e += psum[s2 * 256 + tid];
      }
      float mx = e;
      #pragma unroll
      for (int mm = 32; mm >= 1; mm >>= 1) mx = fmaxf(mx, __shfl_xor(mx, mm, 64));
      if (lane == 0) redC[w] = mx;
      __syncthreads();
      float emax = -INFINITY;
      #pragma unroll
      for (int i = 0; i < 16; i++) emax = fmaxf(emax, redC[i]);
      float pe = (tid < 256) ? expf(e - emax) : 0.f;
      float ps = pe;
      #pragma unroll
      for (int mm = 32; mm >= 1; mm >>= 1) ps += __shfl_xor(ps, mm, 64);
      if (lane == 0) redD[w] = ps;
      __syncthreads();
      float esum = 0.f;
      #pragma unroll
      for (int i = 0; i < 16; i++) esum += redD[i];
      if (tid < 256) comp_f[tid] = pe / esum;
    }
    __syncthreads();

    // ---------- Phase E: write-LSTM ----------
    if (tid < 128) xh[tid] = packf16(comp_f[2 * tid], comp_f[2 * tid + 1]);
    else if (tid < 256){
      int j = tid - 128;
      xh[tid] = packf16(hw_f[2 * j], hw_f[2 * j + 1]);
    }
    __syncthreads();
    gemv1024(WEp, xh, psum, tid);
    __syncthreads();
    gbuf[tid] = psum[tid] + psum[1024 + tid] + psum[2048 + tid]
              + psum[3072 + tid] + bE[tid];
    __syncthreads();
    if (tid < 256){
      float i_ = 1.f / (1.f + expf(-gbuf[tid]));
      float f_ = 1.f / (1.f + expf(-gbuf[256 + tid]));
      float g_ = tanhf(gbuf[512 + tid]);
      float o_ = 1.f / (1.f + expf(-gbuf[768 + tid]));
      float c2 = f_ * cw_l[tid] + i_ * g_;
      cw_l[tid] = c2;
      float h2v = o_ * tanhf(c2);
      hw_f[tid] = h2v;
      out[(size_t)t * 32768 + b * 256 + tid] = h2v;
    }
    __syncthreads();
  }

  // ---------- epilogue: states + M = (1-z) + hw (x) z ----------
  if (tid < 256){
    out[OUT_STATES          + b * 256 + tid] = hr_f[tid];
    out[OUT_STATES +  32768 + b * 256 + tid] = cr_l[tid];
    out[OUT_STATES +  65536 + b * 256 + tid] = hw_f[tid];
    out[OUT_STATES +  98304 + b * 256 + tid] = cw_l[tid];
  }
  z_lds[tid] = zreg;
  __syncthreads();
  float* Mout = out + OUT_M + (size_t)b * 262144;
  for (int g = tid; g < 65536; g += 1024){
    int l = g >> 6, d0 = (g & 63) << 2;
    float z = z_lds[l], omz = 1.f - z;
    float4 h4 = *(const float4*)&hw_f[d0];
    float4 v;
    v.x = omz + h4.x * z;  v.y = omz + h4.y * z;
    v.z = omz + h4.z * z;  v.w = omz + h4.w * z;
    *(float4*)(Mout + (size_t)l * 256 + d0) = v;
  }
}

extern "C" void kernel_launch(void* const* d_in, const int* in_sizes, int n_in,
                              void* d_out, int out_size, void* d_ws, size_t ws_size,
                              hipStream_t stream){
  const float* emb   = (const float*)d_in[0];
  const float* hr0   = (const float*)d_in[1];
  const float* cr0   = (const float*)d_in[2];
  const float* hw0   = (const float*)d_in[3];
  const float* cw0   = (const float*)d_in[4];
  const float* M0    = (const float*)d_in[5];
  const unsigned char* maskraw = (const unsigned char*)d_in[6];
  const float* Wih_r = (const float*)d_in[7];
  const float* Whh_r = (const float*)d_in[8];
  const float* bih_r = (const float*)d_in[9];
  const float* bhh_r = (const float*)d_in[10];
  const float* Wc    = (const float*)d_in[11];
  const float* bc    = (const float*)d_in[12];
  const float* Wih_w = (const float*)d_in[13];
  const float* Whh_w = (const float*)d_in[14];
  const float* bih_w = (const float*)d_in[15];
  const float* bhh_w = (const float*)d_in[16];
  float* out = (float*)d_out;

  char* ws = (char*)d_ws;
  u32* WAp  = (u32*)(ws);                        // 262144 u32 = 1 MB
  u32* WEp  = (u32*)(ws + 1048576);              // 1 MB
  u32* Wcp  = (u32*)(ws + 2097152);              // 256 KB
  float* bA = (float*)(ws + 2359296);            // 4 KB
  float* bE = (float*)(ws + 2363392);            // 4 KB
  float* bcf= (float*)(ws + 2367488);            // 1 KB
  unsigned char* mbuf = (unsigned char*)(ws + 2368512);  // 128 KB

  k_prep<<<dim3(707), dim3(1024), 0, stream>>>(
      Wih_r, Whh_r, bih_r, bhh_r, Wc, bc, Wih_w, Whh_w, bih_w, bhh_w,
      maskraw, WAp, WEp, Wcp, bA, bE, bcf, mbuf);
  k_main<<<dim3(128), dim3(1024), 0, stream>>>(
      emb, hr0, cr0, hw0, cw0, M0, WAp, WEp, Wcp, bA, bE, bcf, mbuf, out);
}